// Round 2
// baseline (2043.668 us; speedup 1.0000x reference)
//
#include <hip/hip_runtime.h>
#include <hip/hip_bf16.h>

typedef unsigned short u16;
typedef unsigned int u32;

#define NXg 784
#define NYg 480
constexpr int N0c = NXg * NYg;   // 376320
constexpr int N1c = N0c / 4;     // 94080
constexpr int N2c = N0c / 16;    // 23520
constexpr int E0c = 4 * N0c;     // 1505280
constexpr int E1c = 4 * N1c;     // 376320
constexpr int E2c = 4 * N2c;     // 94080

__device__ __forceinline__ float bf2f(u16 v) {
    union { u32 u; float f; } t; t.u = ((u32)v) << 16; return t.f;
}
__device__ __forceinline__ u16 f2bf(float f) {
    union { float f; u32 u; } t; t.f = f;
    u32 u = t.u;
    u32 r = (u + 0x7fffu + ((u >> 16) & 1u)) >> 16;   // RNE
    return (u16)r;
}
// dtype-flexible read of a "float" input: isf32 ? fp32 : bf16
__device__ __forceinline__ float rdf(const void* p, int i, int isf32) {
    if (isf32) return ((const float*)p)[i];
    return bf2f(((const u16*)p)[i]);
}
__device__ __forceinline__ void atomAdd(float* p, float v) {
    __hip_atomic_fetch_add(p, v, __ATOMIC_RELAXED, __HIP_MEMORY_SCOPE_AGENT);
}

// ------------- dtype detection: are float inputs fp32 or packed bf16? -------------
// Low u16 of each word: bf16-packed -> exponent field concentrated in [90,135];
// fp32 -> uniform mantissa bits (~18% band hits). Vote over 256 words.
__global__ void k_detect(const u32* __restrict__ xw, int* __restrict__ flag) {
    __shared__ int cnt;
    if (threadIdx.x == 0) cnt = 0;
    __syncthreads();
    u32 w = xw[threadIdx.x];
    int e = (int)((w >> 7) & 0xFFu);
    int hit = ((e >= 90 && e <= 135) || ((w & 0x7FFFu) == 0u)) ? 1 : 0;
    atomicAdd(&cnt, hit);
    __syncthreads();
    if (threadIdx.x == 0) *flag = (cnt < 192) ? 1 : 0;   // 1 => fp32 inputs
}

// ---------------- degree / dinv ----------------
__global__ void k_fill1(float* __restrict__ D, int n) {
    int i = blockIdx.x * blockDim.x + threadIdx.x;
    if (i < n) D[i] = 1.0f;   // self loop
}
__global__ void k_deg(const int* __restrict__ dst, float* __restrict__ D, int nE) {
    int i = blockIdx.x * blockDim.x + threadIdx.x;
    if (i < nE) atomAdd(&D[dst[i]], 1.0f);
}
__global__ void k_rsqrt(float* __restrict__ D, int n) {
    int i = blockIdx.x * blockDim.x + threadIdx.x;
    if (i < n) D[i] = rsqrtf(D[i]);
}

// ---------------- fc1 + relu ----------------
__global__ void k_fc1(const void* __restrict__ x, const void* __restrict__ w,
                      const void* __restrict__ b, float* __restrict__ H,
                      const int* __restrict__ flag) {
    int isf32 = *flag;
    __shared__ float sx[8 * 4];
    int t = threadIdx.x;
    int nodeBase = blockIdx.x * 8;
    if (t < 32) {
        int gi = nodeBase * 4 + t;
        sx[t] = (gi < N0c * 4) ? rdf(x, gi, isf32) : 0.0f;
    }
    __syncthreads();
    int local = t >> 5, c = t & 31;
    int node = nodeBase + local;
    if (node >= N0c) return;
    float a = rdf(b, c, isf32);
#pragma unroll
    for (int k = 0; k < 4; k++) a = fmaf(sx[local * 4 + k], rdf(w, k * 32 + c, isf32), a);
    H[(size_t)node * 32 + c] = fmaxf(a, 0.0f);
}

// ---------------- GCN prep: y = X@W ; XA (acc, aliased onto X) = y*dinv^2 ----------------
// Each block reads only its own 8 rows of XA into LDS before overwriting them -> alias-safe.
__global__ void k_prep(float* XA, const void* __restrict__ w,
                       const float* __restrict__ dinv, float* __restrict__ y,
                       const int* __restrict__ flag, int n) {
    int isf32 = *flag;
    __shared__ float sx[8 * 32];
    int t = threadIdx.x;
    int nodeBase = blockIdx.x * 8;
    int gi = nodeBase * 32 + t;
    sx[t] = (gi < n * 32) ? XA[gi] : 0.0f;
    __syncthreads();
    int local = t >> 5, c = t & 31;
    int node = nodeBase + local;
    if (node >= n) return;
    float a = 0.0f;
#pragma unroll
    for (int k = 0; k < 32; k++) a = fmaf(sx[local * 32 + k], rdf(w, k * 32 + c, isf32), a);
    float di = dinv[node];
    size_t o = (size_t)node * 32 + c;
    y[o] = a;
    XA[o] = a * di * di;   // self-loop term
}

// ---------------- edge scatter: acc[dst] += y[src]*dinv[src]*dinv[dst] ----------------
__global__ void k_scatter(const int* __restrict__ src, const int* __restrict__ dst,
                          const float* __restrict__ dinv, const float* __restrict__ y,
                          float* __restrict__ acc, int nE) {
    int t = blockIdx.x * blockDim.x + threadIdx.x;
    int e = t >> 3, q = t & 7;
    if (e >= nE) return;
    int s = src[e], d = dst[e];
    float nrm = dinv[s] * dinv[d];
    float4 v = ((const float4*)y)[(size_t)s * 8 + q];
    float* a = acc + (size_t)d * 32 + (size_t)q * 4;
    atomAdd(a + 0, v.x * nrm);
    atomAdd(a + 1, v.y * nrm);
    atomAdd(a + 2, v.z * nrm);
    atomAdd(a + 3, v.w * nrm);
}

// ---------------- post: O = relu(acc + b) in place, fused downsample write ----------------
__global__ void k_post_ds(float* acc, const void* __restrict__ b,
                          float* __restrict__ Od, int n, int cols,
                          const int* __restrict__ flag) {
    int isf32 = *flag;
    int gid = blockIdx.x * blockDim.x + threadIdx.x;
    int node = gid >> 5, c = gid & 31;
    if (node >= n) return;
    float v = fmaxf(acc[(size_t)node * 32 + c] + rdf(b, c, isf32), 0.0f);
    acc[(size_t)node * 32 + c] = v;
    int r = node / cols, cc = node - r * cols;
    if (!(r & 1) && !(cc & 1)) {
        int dn = (r >> 1) * (cols >> 1) + (cc >> 1);
        Od[(size_t)dn * 32 + c] = v;
    }
}

// ---------------- post: v = relu(acc + b); T[4 children] += v (upsample residual) ----------------
__global__ void k_post_up(const float* __restrict__ acc, const void* __restrict__ b,
                          float* __restrict__ T, int n, int cols,
                          const int* __restrict__ flag) {
    int isf32 = *flag;
    int gid = blockIdx.x * blockDim.x + threadIdx.x;
    int node = gid >> 5, c = gid & 31;
    if (node >= n) return;
    float v = fmaxf(acc[(size_t)node * 32 + c] + rdf(b, c, isf32), 0.0f);
    int r = node / cols, cc = node - r * cols;
    int upcols = cols * 2;
    size_t base = ((size_t)(2 * r) * upcols + 2 * cc) * 32 + c;
    T[base] += v;
    T[base + 32] += v;
    T[base + (size_t)upcols * 32] += v;
    T[base + (size_t)upcols * 32 + 32] += v;
}

// ---------------- post: final gcn5 relu + fc2 -> out (dtype per flag) ----------------
__global__ void k_post_fc2(const float* __restrict__ acc, const void* __restrict__ b5,
                           const void* __restrict__ fw, const void* __restrict__ fb,
                           void* __restrict__ out, int n, const int* __restrict__ flag) {
    int isf32 = *flag;
    __shared__ float sb[32], sw[96], sfb[3];
    int t = threadIdx.x;
    if (t < 32) sb[t] = rdf(b5, t, isf32);
    if (t < 96) sw[t] = rdf(fw, t, isf32);
    if (t < 3) sfb[t] = rdf(fb, t, isf32);
    __syncthreads();
    int i = blockIdx.x * blockDim.x + t;
    if (i >= n) return;
    const float4* ai = (const float4*)(acc + (size_t)i * 32);
    float o0 = sfb[0], o1 = sfb[1], o2 = sfb[2];
#pragma unroll
    for (int k4 = 0; k4 < 8; k4++) {
        float4 v = ai[k4];
        float vv[4] = {v.x, v.y, v.z, v.w};
#pragma unroll
        for (int j = 0; j < 4; j++) {
            int k = k4 * 4 + j;
            float tt = fmaxf(vv[j] + sb[k], 0.0f);
            o0 = fmaf(tt, sw[k * 3 + 0], o0);
            o1 = fmaf(tt, sw[k * 3 + 1], o1);
            o2 = fmaf(tt, sw[k * 3 + 2], o2);
        }
    }
    if (isf32) {
        float* of = (float*)out;
        of[(size_t)i * 3 + 0] = o0;
        of[(size_t)i * 3 + 1] = o1;
        of[(size_t)i * 3 + 2] = o2;
    } else {
        u16* ob = (u16*)out;
        ob[(size_t)i * 3 + 0] = f2bf(o0);
        ob[(size_t)i * 3 + 1] = f2bf(o1);
        ob[(size_t)i * 3 + 2] = f2bf(o2);
    }
}

extern "C" void kernel_launch(void* const* d_in, const int* in_sizes, int n_in,
                              void* d_out, int out_size, void* d_ws, size_t ws_size,
                              hipStream_t stream) {
    const void* x    = d_in[0];
    const void* fc1w = d_in[1];
    const void* fc1b = d_in[2];
    const void* w1 = d_in[3];  const void* b1 = d_in[4];
    const void* w2 = d_in[5];  const void* b2 = d_in[6];
    const void* w3 = d_in[7];  const void* b3 = d_in[8];
    const void* w4 = d_in[9];  const void* b4 = d_in[10];
    const void* w5 = d_in[11]; const void* b5 = d_in[12];
    const void* fc2w = d_in[13]; const void* fc2b = d_in[14];
    const int* ei0 = (const int*)d_in[18];
    const int* ei1 = (const int*)d_in[19];
    const int* ei2 = (const int*)d_in[20];

    float* ws = (float*)d_ws;
    float* A   = ws;                         // N0*32  (level-0 h; also GCN1/5 acc)
    float* B   = A  + (size_t)N0c * 32;      // N0*32  (Y buffer, all levels)
    float* H1  = B  + (size_t)N0c * 32;      // N1*32  (also GCN2/4 acc)
    float* H2  = H1 + (size_t)N1c * 32;      // N2*32  (also GCN3 acc)
    float* D   = H2 + (size_t)N2c * 32;      // N0+N1+N2
    float* D0 = D;
    float* D1 = D0 + N0c;
    float* D2 = D1 + N1c;
    int* FLAG = (int*)(D + (size_t)(N0c + N1c + N2c));

    const int Bk = 256;
    const int NT = N0c + N1c + N2c;
    auto cdiv = [](int a, int b) { return (a + b - 1) / b; };

    k_detect<<<1, 256, 0, stream>>>((const u32*)x, FLAG);

    // degrees -> dinv (all levels)
    k_fill1<<<cdiv(NT, Bk), Bk, 0, stream>>>(D, NT);
    k_deg<<<cdiv(E0c, Bk), Bk, 0, stream>>>(ei0 + E0c, D0, E0c);
    k_deg<<<cdiv(E1c, Bk), Bk, 0, stream>>>(ei1 + E1c, D1, E1c);
    k_deg<<<cdiv(E2c, Bk), Bk, 0, stream>>>(ei2 + E2c, D2, E2c);
    k_rsqrt<<<cdiv(NT, Bk), Bk, 0, stream>>>(D, NT);

    // fc1 + relu -> A
    k_fc1<<<cdiv(N0c, 8), Bk, 0, stream>>>(x, fc1w, fc1b, A, FLAG);

    // GCN1 (level 0): acc in A, post relu in place + downsample -> H1
    k_prep<<<cdiv(N0c, 8), Bk, 0, stream>>>(A, w1, D0, B, FLAG, N0c);
    k_scatter<<<cdiv(E0c * 8, Bk), Bk, 0, stream>>>(ei0, ei0 + E0c, D0, B, A, E0c);
    k_post_ds<<<cdiv(N0c * 32, Bk), Bk, 0, stream>>>(A, b1, H1, N0c, NYg, FLAG);

    // GCN2 (level 1): acc in H1, post relu in place + downsample -> H2
    k_prep<<<cdiv(N1c, 8), Bk, 0, stream>>>(H1, w2, D1, B, FLAG, N1c);
    k_scatter<<<cdiv(E1c * 8, Bk), Bk, 0, stream>>>(ei1, ei1 + E1c, D1, B, H1, E1c);
    k_post_ds<<<cdiv(N1c * 32, Bk), Bk, 0, stream>>>(H1, b2, H2, N1c, NYg / 2, FLAG);

    // GCN3 (level 2): acc in H2, post relu + upsample residual into H1
    k_prep<<<cdiv(N2c, 8), Bk, 0, stream>>>(H2, w3, D2, B, FLAG, N2c);
    k_scatter<<<cdiv(E2c * 8, Bk), Bk, 0, stream>>>(ei2, ei2 + E2c, D2, B, H2, E2c);
    k_post_up<<<cdiv(N2c * 32, Bk), Bk, 0, stream>>>(H2, b3, H1, N2c, NYg / 4, FLAG);

    // GCN4 (level 1): acc in H1, post relu + upsample residual into A
    k_prep<<<cdiv(N1c, 8), Bk, 0, stream>>>(H1, w4, D1, B, FLAG, N1c);
    k_scatter<<<cdiv(E1c * 8, Bk), Bk, 0, stream>>>(ei1, ei1 + E1c, D1, B, H1, E1c);
    k_post_up<<<cdiv(N1c * 32, Bk), Bk, 0, stream>>>(H1, b4, A, N1c, NYg / 2, FLAG);

    // GCN5 (level 0): acc in A, post fc2 -> d_out
    k_prep<<<cdiv(N0c, 8), Bk, 0, stream>>>(A, w5, D0, B, FLAG, N0c);
    k_scatter<<<cdiv(E0c * 8, Bk), Bk, 0, stream>>>(ei0, ei0 + E0c, D0, B, A, E0c);
    k_post_fc2<<<cdiv(N0c, Bk), Bk, 0, stream>>>(A, b5, fc2w, fc2b, d_out, N0c, FLAG);
}

// Round 3
// 863.430 us; speedup vs baseline: 2.3669x; 2.3669x over previous
//
#include <hip/hip_runtime.h>
#include <hip/hip_bf16.h>

typedef unsigned short u16;
typedef unsigned int u32;

#define NXg 784
#define NYg 480
constexpr int N0c = NXg * NYg;   // 376320
constexpr int N1c = N0c / 4;     // 94080
constexpr int N2c = N0c / 16;    // 23520
constexpr int NTc = N0c + N1c + N2c;
constexpr int E0c = 4 * N0c;     // 1505280
constexpr int E1c = 4 * N1c;     // 376320
constexpr int E2c = 4 * N2c;     // 94080

__device__ __forceinline__ float bf2f(u16 v) {
    union { u32 u; float f; } t; t.u = ((u32)v) << 16; return t.f;
}
__device__ __forceinline__ u16 f2bf(float f) {
    union { float f; u32 u; } t; t.f = f;
    u32 u = t.u;
    u32 r = (u + 0x7fffu + ((u >> 16) & 1u)) >> 16;   // RNE
    return (u16)r;
}
__device__ __forceinline__ float rdf(const void* p, int i, int isf32) {
    if (isf32) return ((const float*)p)[i];
    return bf2f(((const u16*)p)[i]);
}

// ------------- dtype detection: float inputs fp32 or packed bf16? -------------
__global__ void k_detect(const u32* __restrict__ xw, int* __restrict__ flag) {
    __shared__ int cnt;
    if (threadIdx.x == 0) cnt = 0;
    __syncthreads();
    u32 w = xw[threadIdx.x];
    int e = (int)((w >> 7) & 0xFFu);
    int hit = ((e >= 90 && e <= 135) || ((w & 0x7FFFu) == 0u)) ? 1 : 0;
    atomicAdd(&cnt, hit);
    __syncthreads();
    if (threadIdx.x == 0) *flag = (cnt < 192) ? 1 : 0;   // 1 => fp32 inputs
}

// ---------------- CSR build ----------------
__global__ void k_zero(int* __restrict__ c, int n) {
    int i = blockIdx.x * blockDim.x + threadIdx.x;
    if (i < n) c[i] = 0;
}
__global__ void k_hist(const int* __restrict__ dst, int* __restrict__ cnt, int nE) {
    int i = blockIdx.x * blockDim.x + threadIdx.x;
    if (i < nE) atomicAdd(&cnt[dst[i]], 1);
}
__global__ void k_dinv(const int* __restrict__ cnt, float* __restrict__ dv, int n) {
    int i = blockIdx.x * blockDim.x + threadIdx.x;
    if (i < n) dv[i] = rsqrtf((float)cnt[i] + 1.0f);   // +1 self loop
}
// block-level exclusive scan (256/block) with block sums
__global__ void k_scan_block(const int* __restrict__ cnt, int* __restrict__ excl,
                             int* __restrict__ bsum, int n) {
    __shared__ int s[256];
    int i = blockIdx.x * 256 + threadIdx.x;
    int v = (i < n) ? cnt[i] : 0;
    s[threadIdx.x] = v;
    __syncthreads();
    for (int off = 1; off < 256; off <<= 1) {
        int t = (threadIdx.x >= (unsigned)off) ? s[threadIdx.x - off] : 0;
        __syncthreads();
        s[threadIdx.x] += t;
        __syncthreads();
    }
    if (i < n) excl[i] = s[threadIdx.x] - v;
    if (threadIdx.x == 255) bsum[blockIdx.x] = s[255];
}
// single-block scan of block sums (exclusive, with carry across chunks)
__global__ void k_scan_sums(int* __restrict__ bsum, int nb) {
    __shared__ int s[256];
    __shared__ int carry;
    if (threadIdx.x == 0) carry = 0;
    __syncthreads();
    for (int base = 0; base < nb; base += 256) {
        int i = base + threadIdx.x;
        int v = (i < nb) ? bsum[i] : 0;
        s[threadIdx.x] = v;
        __syncthreads();
        for (int off = 1; off < 256; off <<= 1) {
            int t = (threadIdx.x >= (unsigned)off) ? s[threadIdx.x - off] : 0;
            __syncthreads();
            s[threadIdx.x] += t;
            __syncthreads();
        }
        if (i < nb) bsum[i] = s[threadIdx.x] - v + carry;
        __syncthreads();
        if (threadIdx.x == 0) carry += s[255];
        __syncthreads();
    }
}
// add block offsets -> rowptr; also copy to cursor; set rowptr[n]=E
__global__ void k_scan_add(int* __restrict__ rowptr, const int* __restrict__ bsum,
                           int* __restrict__ cursor, int n, int E) {
    int i = blockIdx.x * 256 + threadIdx.x;
    if (i < n) {
        int v = rowptr[i] + bsum[blockIdx.x];
        rowptr[i] = v;
        cursor[i] = v;
    }
    if (i == 0) rowptr[n] = E;
}
__global__ void k_bucket(const int* __restrict__ src, const int* __restrict__ dst,
                         int* __restrict__ cursor, int* __restrict__ col, int nE) {
    int i = blockIdx.x * blockDim.x + threadIdx.x;
    if (i < nE) {
        int pos = atomicAdd(&cursor[dst[i]], 1);
        col[pos] = src[i];
    }
}

// ---------------- fc1 + relu ----------------
__global__ void k_fc1(const void* __restrict__ x, const void* __restrict__ w,
                      const void* __restrict__ b, float* __restrict__ H,
                      const int* __restrict__ flag) {
    int isf32 = *flag;
    __shared__ float sx[8 * 4];
    int t = threadIdx.x;
    int nodeBase = blockIdx.x * 8;
    if (t < 32) {
        int gi = nodeBase * 4 + t;
        sx[t] = (gi < N0c * 4) ? rdf(x, gi, isf32) : 0.0f;
    }
    __syncthreads();
    int local = t >> 5, c = t & 31;
    int node = nodeBase + local;
    if (node >= N0c) return;
    float a = rdf(b, c, isf32);
#pragma unroll
    for (int k = 0; k < 4; k++) a = fmaf(sx[local * 4 + k], rdf(w, k * 32 + c, isf32), a);
    H[(size_t)node * 32 + c] = fmaxf(a, 0.0f);
}

// ---------------- GCN prep: ys = (X@W) * dinv[node] ----------------
__global__ void k_prep(const float* __restrict__ X, const void* __restrict__ w,
                       const float* __restrict__ dinv, float* __restrict__ ys,
                       const int* __restrict__ flag, int n) {
    int isf32 = *flag;
    __shared__ float sx[8 * 32];
    int t = threadIdx.x;
    int nodeBase = blockIdx.x * 8;
    int gi = nodeBase * 32 + t;
    sx[t] = (gi < n * 32) ? X[gi] : 0.0f;
    __syncthreads();
    int local = t >> 5, c = t & 31;
    int node = nodeBase + local;
    if (node >= n) return;
    float a = 0.0f;
#pragma unroll
    for (int k = 0; k < 32; k++) a = fmaf(sx[local * 32 + k], rdf(w, k * 32 + c, isf32), a);
    ys[(size_t)node * 32 + c] = a * dinv[node];
}

// ---------------- gather core: v = relu(di*(ys[node]+sum ys[src]) + b) ----------------
__device__ __forceinline__ float gather_v(const float* __restrict__ ys,
                                          const int* __restrict__ rowptr,
                                          const int* __restrict__ col,
                                          const float* __restrict__ dinv,
                                          const void* __restrict__ b,
                                          int node, int c, int isf32) {
    int s0 = rowptr[node], s1 = rowptr[node + 1];
    float a = ys[(size_t)node * 32 + c];
    for (int e = s0; e < s1; e++) a += ys[(size_t)col[e] * 32 + c];
    return fmaxf(a * dinv[node] + rdf(b, c, isf32), 0.0f);
}

// gather + relu -> O, fused downsample write -> Od
__global__ void k_gather_ds(const float* __restrict__ ys, const int* __restrict__ rowptr,
                            const int* __restrict__ col, const float* __restrict__ dinv,
                            const void* __restrict__ b, float* __restrict__ O,
                            float* __restrict__ Od, int n, int cols,
                            const int* __restrict__ flag) {
    int isf32 = *flag;
    int gid = blockIdx.x * blockDim.x + threadIdx.x;
    int node = gid >> 5, c = gid & 31;
    if (node >= n) return;
    float v = gather_v(ys, rowptr, col, dinv, b, node, c, isf32);
    O[(size_t)node * 32 + c] = v;
    int r = node / cols, cc = node - r * cols;
    if (!(r & 1) && !(cc & 1)) {
        Od[((size_t)((r >> 1) * (cols >> 1) + (cc >> 1))) * 32 + c] = v;
    }
}

// gather + relu; upsample residual: T[4 children] += v (no own-output store)
__global__ void k_gather_up(const float* __restrict__ ys, const int* __restrict__ rowptr,
                            const int* __restrict__ col, const float* __restrict__ dinv,
                            const void* __restrict__ b, float* __restrict__ T,
                            int n, int cols, const int* __restrict__ flag) {
    int isf32 = *flag;
    int gid = blockIdx.x * blockDim.x + threadIdx.x;
    int node = gid >> 5, c = gid & 31;
    if (node >= n) return;
    float v = gather_v(ys, rowptr, col, dinv, b, node, c, isf32);
    int r = node / cols, cc = node - r * cols;
    int upcols = cols * 2;
    size_t base = ((size_t)(2 * r) * upcols + 2 * cc) * 32 + c;
    T[base] += v;
    T[base + 32] += v;
    T[base + (size_t)upcols * 32] += v;
    T[base + (size_t)upcols * 32 + 32] += v;
}

// gather + relu + fc2 -> out (final)
__global__ void k_gather_fc2(const float* __restrict__ ys, const int* __restrict__ rowptr,
                             const int* __restrict__ col, const float* __restrict__ dinv,
                             const void* __restrict__ b5, const void* __restrict__ fw,
                             const void* __restrict__ fb, void* __restrict__ out,
                             int n, const int* __restrict__ flag) {
    int isf32 = *flag;
    __shared__ float sv[8 * 32];
    __shared__ float sw[96];
    __shared__ float sfb[3];
    int t = threadIdx.x;
    if (t < 96) sw[t] = rdf(fw, t, isf32);
    if (t < 3) sfb[t] = rdf(fb, t, isf32);
    int node = blockIdx.x * 8 + (t >> 5);
    int c = t & 31;
    float v = 0.0f;
    if (node < n) v = gather_v(ys, rowptr, col, dinv, b5, node, c, isf32);
    sv[t] = v;
    __syncthreads();
    if (t < 24) {
        int ln = t / 3, j = t - ln * 3;
        int gn = blockIdx.x * 8 + ln;
        if (gn < n) {
            float o = sfb[j];
#pragma unroll
            for (int k = 0; k < 32; k++) o = fmaf(sv[ln * 32 + k], sw[k * 3 + j], o);
            if (isf32) ((float*)out)[(size_t)gn * 3 + j] = o;
            else ((u16*)out)[(size_t)gn * 3 + j] = f2bf(o);
        }
    }
}

extern "C" void kernel_launch(void* const* d_in, const int* in_sizes, int n_in,
                              void* d_out, int out_size, void* d_ws, size_t ws_size,
                              hipStream_t stream) {
    const void* x    = d_in[0];
    const void* fc1w = d_in[1];
    const void* fc1b = d_in[2];
    const void* w1 = d_in[3];  const void* b1 = d_in[4];
    const void* w2 = d_in[5];  const void* b2 = d_in[6];
    const void* w3 = d_in[7];  const void* b3 = d_in[8];
    const void* w4 = d_in[9];  const void* b4 = d_in[10];
    const void* w5 = d_in[11]; const void* b5 = d_in[12];
    const void* fc2w = d_in[13]; const void* fc2b = d_in[14];
    const int* ei0 = (const int*)d_in[18];
    const int* ei1 = (const int*)d_in[19];
    const int* ei2 = (const int*)d_in[20];

    float* ws = (float*)d_ws;
    float* A    = ws;                        // N0*32: level-0 h
    float* B    = A  + (size_t)N0c * 32;     // N0*32: ys scratch (build-phase: cursor/bsum)
    float* H1   = B  + (size_t)N0c * 32;     // N1*32
    float* H2   = H1 + (size_t)N1c * 32;     // N2*32
    float* DINV = H2 + (size_t)N2c * 32;     // NT
    int* CNT  = (int*)(DINV + NTc);          // NT
    int* RP0  = CNT + NTc;                   // N0+1
    int* RP1  = RP0 + (N0c + 1);             // N1+1
    int* RP2  = RP1 + (N1c + 1);             // N2+1
    int* COL0 = RP2 + (N2c + 1);             // E0
    int* COL1 = COL0 + E0c;                  // E1
    int* COL2 = COL1 + E1c;                  // E2
    int* FLAG = COL2 + E2c;                  // 1
    // build-phase scratch inside B (ys not live yet)
    int* CURSOR = (int*)B;                   // max N0 ints
    int* BSUM   = CURSOR + N0c;              // max 1470 ints

    float* D0 = DINV;
    float* D1 = D0 + N0c;
    float* D2 = D1 + N1c;
    int* C0 = CNT;
    int* C1 = C0 + N0c;
    int* C2 = C1 + N1c;

    const int Bk = 256;
    auto cdiv = [](int a, int b) { return (a + b - 1) / b; };

    k_detect<<<1, 256, 0, stream>>>((const u32*)x, FLAG);

    // degree histogram (all levels) -> dinv
    k_zero<<<cdiv(NTc, Bk), Bk, 0, stream>>>(CNT, NTc);
    k_hist<<<cdiv(E0c, Bk), Bk, 0, stream>>>(ei0 + E0c, C0, E0c);
    k_hist<<<cdiv(E1c, Bk), Bk, 0, stream>>>(ei1 + E1c, C1, E1c);
    k_hist<<<cdiv(E2c, Bk), Bk, 0, stream>>>(ei2 + E2c, C2, E2c);
    k_dinv<<<cdiv(NTc, Bk), Bk, 0, stream>>>(CNT, DINV, NTc);

    // CSR per level (sequential on stream; scratch reused)
    {   // level 0
        int nb = cdiv(N0c, 256);
        k_scan_block<<<nb, 256, 0, stream>>>(C0, RP0, BSUM, N0c);
        k_scan_sums<<<1, 256, 0, stream>>>(BSUM, nb);
        k_scan_add<<<nb, 256, 0, stream>>>(RP0, BSUM, CURSOR, N0c, E0c);
        k_bucket<<<cdiv(E0c, Bk), Bk, 0, stream>>>(ei0, ei0 + E0c, CURSOR, COL0, E0c);
    }
    {   // level 1
        int nb = cdiv(N1c, 256);
        k_scan_block<<<nb, 256, 0, stream>>>(C1, RP1, BSUM, N1c);
        k_scan_sums<<<1, 256, 0, stream>>>(BSUM, nb);
        k_scan_add<<<nb, 256, 0, stream>>>(RP1, BSUM, CURSOR, N1c, E1c);
        k_bucket<<<cdiv(E1c, Bk), Bk, 0, stream>>>(ei1, ei1 + E1c, CURSOR, COL1, E1c);
    }
    {   // level 2
        int nb = cdiv(N2c, 256);
        k_scan_block<<<nb, 256, 0, stream>>>(C2, RP2, BSUM, N2c);
        k_scan_sums<<<1, 256, 0, stream>>>(BSUM, nb);
        k_scan_add<<<nb, 256, 0, stream>>>(RP2, BSUM, CURSOR, N2c, E2c);
        k_bucket<<<cdiv(E2c, Bk), Bk, 0, stream>>>(ei2, ei2 + E2c, CURSOR, COL2, E2c);
    }

    // fc1 + relu -> A
    k_fc1<<<cdiv(N0c, 8), Bk, 0, stream>>>(x, fc1w, fc1b, A, FLAG);

    // GCN1 (level 0): A -> ys(B) -> gather -> A (in place) + downsample H1
    k_prep<<<cdiv(N0c, 8), Bk, 0, stream>>>(A, w1, D0, B, FLAG, N0c);
    k_gather_ds<<<cdiv(N0c * 32, Bk), Bk, 0, stream>>>(B, RP0, COL0, D0, b1, A, H1, N0c, NYg, FLAG);

    // GCN2 (level 1): H1 -> ys(B) -> gather -> H1 + downsample H2
    k_prep<<<cdiv(N1c, 8), Bk, 0, stream>>>(H1, w2, D1, B, FLAG, N1c);
    k_gather_ds<<<cdiv(N1c * 32, Bk), Bk, 0, stream>>>(B, RP1, COL1, D1, b2, H1, H2, N1c, NYg / 2, FLAG);

    // GCN3 (level 2): H2 -> ys(B) -> gather + upsample residual into H1
    k_prep<<<cdiv(N2c, 8), Bk, 0, stream>>>(H2, w3, D2, B, FLAG, N2c);
    k_gather_up<<<cdiv(N2c * 32, Bk), Bk, 0, stream>>>(B, RP2, COL2, D2, b3, H1, N2c, NYg / 4, FLAG);

    // GCN4 (level 1): H1 -> ys(B) -> gather + upsample residual into A
    k_prep<<<cdiv(N1c, 8), Bk, 0, stream>>>(H1, w4, D1, B, FLAG, N1c);
    k_gather_up<<<cdiv(N1c * 32, Bk), Bk, 0, stream>>>(B, RP1, COL1, D1, b4, A, N1c, NYg / 2, FLAG);

    // GCN5 (level 0): A -> ys(B) -> gather + fc2 -> d_out
    k_prep<<<cdiv(N0c, 8), Bk, 0, stream>>>(A, w5, D0, B, FLAG, N0c);
    k_gather_fc2<<<cdiv(N0c, 8), Bk, 0, stream>>>(B, RP0, COL0, D0, b5, fc2w, fc2b, d_out, N0c, FLAG);
}

// Round 4
// 730.504 us; speedup vs baseline: 2.7976x; 1.1820x over previous
//
#include <hip/hip_runtime.h>
#include <hip/hip_bf16.h>

typedef unsigned short u16;
typedef unsigned int u32;

#define NXg 784
#define NYg 480
constexpr int N0c = NXg * NYg;   // 376320
constexpr int N1c = N0c / 4;     // 94080
constexpr int N2c = N0c / 16;    // 23520
constexpr int NTc = N0c + N1c + N2c;
constexpr int E0c = 4 * N0c;     // 1505280
constexpr int E1c = 4 * N1c;     // 376320
constexpr int E2c = 4 * N2c;     // 94080
// padded col capacity (each row padded to multiple of 4)
constexpr int P0c = E0c + 3 * N0c;   // 2634240
constexpr int P1c = E1c + 3 * N1c;   // 658560
constexpr int P2c = E2c + 3 * N2c;   // 164640

__device__ __forceinline__ float bf2f(u16 v) {
    union { u32 u; float f; } t; t.u = ((u32)v) << 16; return t.f;
}
__device__ __forceinline__ u16 f2bf(float f) {
    union { float f; u32 u; } t; t.f = f;
    u32 u = t.u;
    u32 r = (u + 0x7fffu + ((u >> 16) & 1u)) >> 16;   // RNE
    return (u16)r;
}
__device__ __forceinline__ float rdf(const void* p, int i, int isf32) {
    if (isf32) return ((const float*)p)[i];
    return bf2f(((const u16*)p)[i]);
}

// ------------- dtype detection -------------
__global__ void k_detect(const u32* __restrict__ xw, int* __restrict__ flag) {
    __shared__ int cnt;
    if (threadIdx.x == 0) cnt = 0;
    __syncthreads();
    u32 w = xw[threadIdx.x];
    int e = (int)((w >> 7) & 0xFFu);
    int hit = ((e >= 90 && e <= 135) || ((w & 0x7FFFu) == 0u)) ? 1 : 0;
    atomicAdd(&cnt, hit);
    __syncthreads();
    if (threadIdx.x == 0) *flag = (cnt < 192) ? 1 : 0;   // 1 => fp32 inputs
}

// ---------------- CSR build ----------------
__global__ void k_zero(int* __restrict__ c, int n) {
    int i = blockIdx.x * blockDim.x + threadIdx.x;
    if (i < n) c[i] = 0;
}
__global__ void k_filln(int* __restrict__ c, int val, int n) {
    int i = blockIdx.x * blockDim.x + threadIdx.x;
    if (i < n) c[i] = val;
}
__global__ void k_zerof(float* __restrict__ p, int n) {
    int i = blockIdx.x * blockDim.x + threadIdx.x;
    if (i < n) p[i] = 0.0f;
}
__global__ void k_hist(const int* __restrict__ dst, int* __restrict__ cnt, int nE) {
    int i = blockIdx.x * blockDim.x + threadIdx.x;
    if (i < nE) atomicAdd(&cnt[dst[i]], 1);
}
__global__ void k_dinv(const int* __restrict__ cnt, float* __restrict__ dv, int n) {
    int i = blockIdx.x * blockDim.x + threadIdx.x;
    if (i < n) dv[i] = rsqrtf((float)cnt[i] + 1.0f);   // +1 self loop
}
// exclusive scan of PADDED counts ((cnt+3)&~3), 256/block, emits block sums
__global__ void k_scan_block(const int* __restrict__ cnt, int* __restrict__ excl,
                             int* __restrict__ bsum, int n) {
    __shared__ int s[256];
    int i = blockIdx.x * 256 + threadIdx.x;
    int v = (i < n) ? ((cnt[i] + 3) & ~3) : 0;
    s[threadIdx.x] = v;
    __syncthreads();
    for (int off = 1; off < 256; off <<= 1) {
        int t = (threadIdx.x >= (unsigned)off) ? s[threadIdx.x - off] : 0;
        __syncthreads();
        s[threadIdx.x] += t;
        __syncthreads();
    }
    if (i < n) excl[i] = s[threadIdx.x] - v;
    if (threadIdx.x == 255) bsum[blockIdx.x] = s[255];
}
__global__ void k_scan_sums(int* __restrict__ bsum, int nb) {
    __shared__ int s[256];
    __shared__ int carry;
    if (threadIdx.x == 0) carry = 0;
    __syncthreads();
    for (int base = 0; base < nb; base += 256) {
        int i = base + threadIdx.x;
        int v = (i < nb) ? bsum[i] : 0;
        s[threadIdx.x] = v;
        __syncthreads();
        for (int off = 1; off < 256; off <<= 1) {
            int t = (threadIdx.x >= (unsigned)off) ? s[threadIdx.x - off] : 0;
            __syncthreads();
            s[threadIdx.x] += t;
            __syncthreads();
        }
        if (i < nb) bsum[i] = s[threadIdx.x] - v + carry;
        __syncthreads();
        if (threadIdx.x == 0) carry += s[255];
        __syncthreads();
    }
}
__global__ void k_scan_add(int* __restrict__ rowptr, const int* __restrict__ bsum,
                           int* __restrict__ cursor, int n) {
    int i = blockIdx.x * 256 + threadIdx.x;
    if (i < n) {
        int v = rowptr[i] + bsum[blockIdx.x];
        rowptr[i] = v;
        cursor[i] = v;
    }
}
__global__ void k_bucket(const int* __restrict__ src, const int* __restrict__ dst,
                         int* __restrict__ cursor, int* __restrict__ col, int nE) {
    int i = blockIdx.x * blockDim.x + threadIdx.x;
    if (i < nE) {
        int pos = atomicAdd(&cursor[dst[i]], 1);
        col[pos] = src[i];
    }
}

// ---------------- gather core: a = (ys[node] + sum ys[col]) * dinv[node] ----------------
// padded CSR: row starts at rp[node] (mult of 4), ceil(cnt/4) int4 chunks, dummies -> zero row
__device__ __forceinline__ float gather4(const float* __restrict__ ys,
                                         const int* __restrict__ rp,
                                         const int* __restrict__ cnt,
                                         const int* __restrict__ col,
                                         const float* __restrict__ dinv,
                                         int node, int c) {
    int s0 = rp[node];
    int nch = (cnt[node] + 3) >> 2;
    float a = ys[(size_t)node * 32 + c];
    const int4* c4 = (const int4*)(col + s0);
    for (int i = 0; i < nch; i++) {
        int4 cs = c4[i];
        float a0 = ys[(size_t)cs.x * 32 + c];
        float a1 = ys[(size_t)cs.y * 32 + c];
        float a2 = ys[(size_t)cs.z * 32 + c];
        float a3 = ys[(size_t)cs.w * 32 + c];
        a += (a0 + a1) + (a2 + a3);
    }
    return a * dinv[node];
}

// ---------------- K1: fc1 + relu + prep1 (ys1 = (h_a@W1)*d0), h_a never stored ----------------
__global__ void k_fc1prep(const void* __restrict__ x, const void* __restrict__ fw,
                          const void* __restrict__ fb, const void* __restrict__ w1,
                          const float* __restrict__ d0, float* __restrict__ ys1,
                          const int* __restrict__ flag) {
    int isf32 = *flag;
    __shared__ float sx[32];
    __shared__ float sh[256];
    int t = threadIdx.x;
    int nodeBase = blockIdx.x * 8;
    if (t < 32) sx[t] = rdf(x, nodeBase * 4 + t, isf32);
    __syncthreads();
    int local = t >> 5, c = t & 31;
    float a = rdf(fb, c, isf32);
#pragma unroll
    for (int k = 0; k < 4; k++) a = fmaf(sx[local * 4 + k], rdf(fw, k * 32 + c, isf32), a);
    sh[t] = fmaxf(a, 0.0f);
    __syncthreads();
    float s = 0.0f;
#pragma unroll
    for (int k = 0; k < 32; k++) s = fmaf(sh[local * 32 + k], rdf(w1, k * 32 + c, isf32), s);
    int node = nodeBase + local;
    ys1[(size_t)node * 32 + c] = s * d0[node];
}

// ---------------- K2/K3: gather + relu -> O(residual); even rows: prep_next on downsample ----------------
__global__ void k_gds(const float* __restrict__ ys_in, const int* __restrict__ rp,
                      const int* __restrict__ cnt, const int* __restrict__ col,
                      const float* __restrict__ dinv_p, const void* __restrict__ b,
                      float* __restrict__ O, const void* __restrict__ wn,
                      const float* __restrict__ dinv_c, float* __restrict__ ys_out,
                      int cols, const int* __restrict__ flag) {
    int isf32 = *flag;
    __shared__ float sv[256];
    int t = threadIdx.x;
    int nodeBase = blockIdx.x * 8;
    int local = t >> 5, c = t & 31;
    int node = nodeBase + local;
    float v = fmaxf(gather4(ys_in, rp, cnt, col, dinv_p, node, c) + rdf(b, c, isf32), 0.0f);
    O[(size_t)node * 32 + c] = v;
    sv[t] = v;
    __syncthreads();
    int rb = nodeBase / cols;
    if (!(rb & 1) && t < 128) {
        int row = t >> 5;            // 0..3 -> local = row*2 (even cc)
        int lc = row * 2;
        int cc = (nodeBase - rb * cols) + lc;
        int dn = (rb >> 1) * (cols >> 1) + (cc >> 1);
        int ci = t & 31;
        float a = 0.0f;
#pragma unroll
        for (int k = 0; k < 32; k++) a = fmaf(sv[lc * 32 + k], rdf(wn, k * 32 + ci, isf32), a);
        ys_out[(size_t)dn * 32 + ci] = a * dinv_c[dn];
    }
}

// ---------------- K4/K5: gather(level p) + up-residual + prep_next for 4 children ----------------
__global__ void k_gup(const float* __restrict__ ys_in, const int* __restrict__ rp,
                      const int* __restrict__ cnt, const int* __restrict__ col,
                      const float* __restrict__ dinv_p, const void* __restrict__ b,
                      const float* __restrict__ R, const void* __restrict__ wn,
                      const float* __restrict__ dinv_c, float* __restrict__ ys_out,
                      int cols_p, const int* __restrict__ flag) {
    int isf32 = *flag;
    __shared__ float sv[256];        // 8 parent rows
    __shared__ float sch[1024];      // 32 child rows
    int t = threadIdx.x;
    int nodeBase = blockIdx.x * 8;
    int local = t >> 5, c = t & 31;
    int node = nodeBase + local;
    float v = fmaxf(gather4(ys_in, rp, cnt, col, dinv_p, node, c) + rdf(b, c, isf32), 0.0f);
    sv[t] = v;
    __syncthreads();
    int rb = nodeBase / cols_p;
    int ccb = nodeBase - rb * cols_p;
    int cols_c = cols_p * 2;
    // Phase B: stage child rows = R[child] + parent v
#pragma unroll
    for (int i = 0; i < 4; i++) {
        int item = t + i * 256;
        int row = item >> 5, k = item & 31;
        int lp = row >> 2, j = row & 3;
        int ch = (2 * rb + (j >> 1)) * cols_c + 2 * (ccb + lp) + (j & 1);
        sch[item] = R[(size_t)ch * 32 + k] + sv[lp * 32 + k];
    }
    __syncthreads();
    // Phase C: ys_out[child] = (child_row @ Wn) * dinv_c[child]
#pragma unroll
    for (int i = 0; i < 4; i++) {
        int item = t + i * 256;
        int row = item >> 5, ci = item & 31;
        int lp = row >> 2, j = row & 3;
        int ch = (2 * rb + (j >> 1)) * cols_c + 2 * (ccb + lp) + (j & 1);
        float a = 0.0f;
#pragma unroll
        for (int k = 0; k < 32; k++) a = fmaf(sch[row * 32 + k], rdf(wn, k * 32 + ci, isf32), a);
        ys_out[(size_t)ch * 32 + ci] = a * dinv_c[ch];
    }
}

// ---------------- K6: gather + relu + fc2 -> out ----------------
__global__ void k_gfc2(const float* __restrict__ ys, const int* __restrict__ rp,
                       const int* __restrict__ cnt, const int* __restrict__ col,
                       const float* __restrict__ dinv, const void* __restrict__ b5,
                       const void* __restrict__ fw, const void* __restrict__ fb,
                       void* __restrict__ out, int n, const int* __restrict__ flag) {
    int isf32 = *flag;
    __shared__ float sv[256];
    __shared__ float sw[96];
    __shared__ float sfb[3];
    int t = threadIdx.x;
    if (t < 96) sw[t] = rdf(fw, t, isf32);
    if (t < 3) sfb[t] = rdf(fb, t, isf32);
    int node = blockIdx.x * 8 + (t >> 5);
    int c = t & 31;
    float v = fmaxf(gather4(ys, rp, cnt, col, dinv, node, c) + rdf(b5, c, isf32), 0.0f);
    sv[t] = v;
    __syncthreads();
    if (t < 24) {
        int ln = t / 3, j = t - ln * 3;
        int gn = blockIdx.x * 8 + ln;
        float o = sfb[j];
#pragma unroll
        for (int k = 0; k < 32; k++) o = fmaf(sv[ln * 32 + k], sw[k * 3 + j], o);
        if (isf32) ((float*)out)[(size_t)gn * 3 + j] = o;
        else ((u16*)out)[(size_t)gn * 3 + j] = f2bf(o);
    }
}

extern "C" void kernel_launch(void* const* d_in, const int* in_sizes, int n_in,
                              void* d_out, int out_size, void* d_ws, size_t ws_size,
                              hipStream_t stream) {
    const void* x    = d_in[0];
    const void* fc1w = d_in[1];
    const void* fc1b = d_in[2];
    const void* w1 = d_in[3];  const void* b1 = d_in[4];
    const void* w2 = d_in[5];  const void* b2 = d_in[6];
    const void* w3 = d_in[7];  const void* b3 = d_in[8];
    const void* w4 = d_in[9];  const void* b4 = d_in[10];
    const void* w5 = d_in[11]; const void* b5 = d_in[12];
    const void* fc2w = d_in[13]; const void* fc2b = d_in[14];
    const int* ei0 = (const int*)d_in[18];
    const int* ei1 = (const int*)d_in[19];
    const int* ei2 = (const int*)d_in[20];

    float* ws = (float*)d_ws;
    float* YS0  = ws;                          // (N0+1)*32
    float* A    = YS0 + (size_t)(N0c + 1) * 32; // N0*32  (h_b residual)
    float* YS1  = A   + (size_t)N0c * 32;       // (N1+1)*32
    float* H1   = YS1 + (size_t)(N1c + 1) * 32; // N1*32  (h1_b residual)
    float* YS2  = H1  + (size_t)N1c * 32;       // (N2+1)*32
    float* DINV = YS2 + (size_t)(N2c + 1) * 32; // NT
    int* CNT  = (int*)(DINV + NTc);             // NT
    int* RP0  = CNT + NTc;                      // N0
    int* RP1  = RP0 + N0c;                      // N1
    int* RP2  = RP1 + N1c;                      // N2
    int* COL0 = RP2 + N2c;                      // P0
    int* COL1 = COL0 + P0c;                     // P1
    int* COL2 = COL1 + P1c;                     // P2
    int* FLAG = COL2 + P2c;                     // 1 (+pad)
    // build-phase scratch inside A (A not live until K2)
    int* CURSOR = (int*)A;
    int* BSUM   = CURSOR + N0c;

    float* D0 = DINV; float* D1 = D0 + N0c; float* D2 = D1 + N1c;
    int* C0 = CNT; int* C1 = C0 + N0c; int* C2 = C1 + N1c;

    const int Bk = 256;
    auto cdiv = [](int a, int b) { return (a + b - 1) / b; };

    k_detect<<<1, 256, 0, stream>>>((const u32*)x, FLAG);

    // degree histogram -> dinv
    k_zero<<<cdiv(NTc, Bk), Bk, 0, stream>>>(CNT, NTc);
    k_hist<<<cdiv(E0c, Bk), Bk, 0, stream>>>(ei0 + E0c, C0, E0c);
    k_hist<<<cdiv(E1c, Bk), Bk, 0, stream>>>(ei1 + E1c, C1, E1c);
    k_hist<<<cdiv(E2c, Bk), Bk, 0, stream>>>(ei2 + E2c, C2, E2c);
    k_dinv<<<cdiv(NTc, Bk), Bk, 0, stream>>>(CNT, DINV, NTc);

    // pre-fill padded col arrays with dummy (zero-row) indices
    k_filln<<<cdiv(P0c, Bk), Bk, 0, stream>>>(COL0, N0c, P0c);
    k_filln<<<cdiv(P1c, Bk), Bk, 0, stream>>>(COL1, N1c, P1c);
    k_filln<<<cdiv(P2c, Bk), Bk, 0, stream>>>(COL2, N2c, P2c);
    // zero the dummy ys rows
    k_zerof<<<1, 96, 0, stream>>>(YS0 + (size_t)N0c * 32, 32);
    k_zerof<<<1, 96, 0, stream>>>(YS1 + (size_t)N1c * 32, 32);
    k_zerof<<<1, 96, 0, stream>>>(YS2 + (size_t)N2c * 32, 32);

    // padded CSR per level
    {
        int nb = cdiv(N0c, 256);
        k_scan_block<<<nb, 256, 0, stream>>>(C0, RP0, BSUM, N0c);
        k_scan_sums<<<1, 256, 0, stream>>>(BSUM, nb);
        k_scan_add<<<nb, 256, 0, stream>>>(RP0, BSUM, CURSOR, N0c);
        k_bucket<<<cdiv(E0c, Bk), Bk, 0, stream>>>(ei0, ei0 + E0c, CURSOR, COL0, E0c);
    }
    {
        int nb = cdiv(N1c, 256);
        k_scan_block<<<nb, 256, 0, stream>>>(C1, RP1, BSUM, N1c);
        k_scan_sums<<<1, 256, 0, stream>>>(BSUM, nb);
        k_scan_add<<<nb, 256, 0, stream>>>(RP1, BSUM, CURSOR, N1c);
        k_bucket<<<cdiv(E1c, Bk), Bk, 0, stream>>>(ei1, ei1 + E1c, CURSOR, COL1, E1c);
    }
    {
        int nb = cdiv(N2c, 256);
        k_scan_block<<<nb, 256, 0, stream>>>(C2, RP2, BSUM, N2c);
        k_scan_sums<<<1, 256, 0, stream>>>(BSUM, nb);
        k_scan_add<<<nb, 256, 0, stream>>>(RP2, BSUM, CURSOR, N2c);
        k_bucket<<<cdiv(E2c, Bk), Bk, 0, stream>>>(ei2, ei2 + E2c, CURSOR, COL2, E2c);
    }

    // K1: fc1+relu+prep1 -> YS0
    k_fc1prep<<<N0c / 8, Bk, 0, stream>>>(x, fc1w, fc1b, w1, D0, YS0, FLAG);
    // K2: gather1 -> A (h_b), fused prep2 on downsample -> YS1
    k_gds<<<N0c / 8, Bk, 0, stream>>>(YS0, RP0, CNT, COL0, D0, b1, A, w2, D1, YS1, NYg, FLAG);
    // K3: gather2 -> H1 (h1_b), fused prep3 on downsample -> YS2
    k_gds<<<N1c / 8, Bk, 0, stream>>>(YS1, RP1, C1, COL1, D1, b2, H1, w3, D2, YS2, NYg / 2, FLAG);
    // K4: gather3 (level2) + up-residual(H1) + prep4 -> YS1
    k_gup<<<N2c / 8, Bk, 0, stream>>>(YS2, RP2, C2, COL2, D2, b3, H1, w4, D1, YS1, NYg / 4, FLAG);
    // K5: gather4 (level1) + up-residual(A) + prep5 -> YS0
    k_gup<<<N1c / 8, Bk, 0, stream>>>(YS1, RP1, C1, COL1, D1, b4, A, w5, D0, YS0, NYg / 2, FLAG);
    // K6: gather5 + fc2 -> out
    k_gfc2<<<N0c / 8, Bk, 0, stream>>>(YS0, RP0, CNT, COL0, D0, b5, fc2w, fc2b, d_out, N0c, FLAG);
}

// Round 5
// 541.133 us; speedup vs baseline: 3.7766x; 1.3500x over previous
//
#include <hip/hip_runtime.h>
#include <hip/hip_bf16.h>

typedef unsigned short u16;
typedef unsigned int u32;

#define NXg 784
#define NYg 480
constexpr int N0c = NXg * NYg;   // 376320
constexpr int N1c = N0c / 4;     // 94080
constexpr int N2c = N0c / 16;    // 23520
constexpr int NTc = N0c + N1c + N2c;
constexpr int E0c = 4 * N0c;     // 1505280
constexpr int E1c = 4 * N1c;     // 376320
constexpr int E2c = 4 * N2c;     // 94080
constexpr int Etot = E0c + E1c + E2c;
// padded col capacity (each row padded to multiple of 4)
constexpr int P0c = E0c + 3 * N0c;
constexpr int P1c = E1c + 3 * N1c;
constexpr int P2c = E2c + 3 * N2c;
constexpr int Ptot = P0c + P1c + P2c;
// bins: 1024 nodes (= 4096 edges avg) per bin
constexpr int NB0 = (N0c + 1023) / 1024;   // 368
constexpr int NB1 = (N1c + 1023) / 1024;   // 92
constexpr int NB2 = (N2c + 1023) / 1024;   // 23
constexpr int NBt = NB0 + NB1 + NB2;       // 483

__device__ __forceinline__ float bf2f(u16 v) {
    union { u32 u; float f; } t; t.u = ((u32)v) << 16; return t.f;
}
__device__ __forceinline__ u16 f2bf(float f) {
    union { float f; u32 u; } t; t.f = f;
    u32 u = t.u;
    u32 r = (u + 0x7fffu + ((u >> 16) & 1u)) >> 16;   // RNE
    return (u16)r;
}
__device__ __forceinline__ float rdf(const void* p, int i, int isf32) {
    if (isf32) return ((const float*)p)[i];
    return bf2f(((const u16*)p)[i]);
}

// resolve bin id -> (level, bin-local, level bin base)
__device__ __forceinline__ void lvl_of_bin(int b, int& lv, int& bl) {
    if (b < NB0) { lv = 0; bl = b; }
    else if (b < NB0 + NB1) { lv = 1; bl = b - NB0; }
    else { lv = 2; bl = b - NB0 - NB1; }
}

// ------------- dtype detection -------------
__global__ void k_detect(const u32* __restrict__ xw, int* __restrict__ flag) {
    __shared__ int cnt;
    if (threadIdx.x == 0) cnt = 0;
    __syncthreads();
    u32 w = xw[threadIdx.x];
    int e = (int)((w >> 7) & 0xFFu);
    int hit = ((e >= 90 && e <= 135) || ((w & 0x7FFFu) == 0u)) ? 1 : 0;
    atomicAdd(&cnt, hit);
    __syncthreads();
    if (threadIdx.x == 0) *flag = (cnt < 192) ? 1 : 0;   // 1 => fp32 inputs
}

// ------------- init: zero bin counters + ys dummy rows -------------
__global__ void k_init(int* __restrict__ binCnt, float* __restrict__ y0,
                       float* __restrict__ y1, float* __restrict__ y2) {
    int t = blockIdx.x * blockDim.x + threadIdx.x;
    if (t < NBt) binCnt[t] = 0;
    if (t < 32) { y0[t] = 0.0f; y1[t] = 0.0f; y2[t] = 0.0f; }
}

// ------------- phase A: bin counts (LDS histogram per 4096-edge chunk) -------------
__global__ void kA_count(const int* __restrict__ ei0, const int* __restrict__ ei1,
                         const int* __restrict__ ei2, int* __restrict__ binCnt) {
    __shared__ int lc[NB0];
    int b = blockIdx.x, t = threadIdx.x;
    int lv, bl; lvl_of_bin(b, lv, bl);
    const int* dstp; int E, nb, binB;
    if (lv == 0) { dstp = ei0 + E0c; E = E0c; nb = NB0; binB = 0; }
    else if (lv == 1) { dstp = ei1 + E1c; E = E1c; nb = NB1; binB = NB0; }
    else { dstp = ei2 + E2c; E = E2c; nb = NB2; binB = NB0 + NB1; }
    for (int i = t; i < nb; i += 256) lc[i] = 0;
    __syncthreads();
    int e0 = bl * 4096, e1 = min(E, e0 + 4096);
    for (int i = e0 + t; i < e1; i += 256) atomicAdd(&lc[dstp[i] >> 10], 1);
    __syncthreads();
    for (int i = t; i < nb; i += 256) if (lc[i]) atomicAdd(&binCnt[binB + i], lc[i]);
}

// ------------- phase B: scan bin counts -> binStart / binCursor -------------
__global__ void kB_scan(const int* __restrict__ binCnt, int* __restrict__ binStart,
                        int* __restrict__ binCursor) {
    __shared__ int s[512];
    int t = threadIdx.x;
    int v = (t < NBt) ? binCnt[t] : 0;
    s[t] = v;
    __syncthreads();
    for (int off = 1; off < 512; off <<= 1) {
        int x = (t >= off) ? s[t - off] : 0;
        __syncthreads();
        s[t] += x;
        __syncthreads();
    }
    if (t < NBt) { int e = s[t] - v; binStart[t] = e; binCursor[t] = e; }
    if (t == 0) binStart[NBt] = Etot;
}

// ------------- phase C: place (src,dst) into bin regions -------------
__global__ void kC_place(const int* __restrict__ ei0, const int* __restrict__ ei1,
                         const int* __restrict__ ei2, int* __restrict__ binCursor,
                         int2* __restrict__ BE) {
    __shared__ int lc[NB0];
    __shared__ int lb[NB0];
    int b = blockIdx.x, t = threadIdx.x;
    int lv, bl; lvl_of_bin(b, lv, bl);
    const int* srcp; const int* dstp; int E, nb, binB;
    if (lv == 0) { srcp = ei0; dstp = ei0 + E0c; E = E0c; nb = NB0; binB = 0; }
    else if (lv == 1) { srcp = ei1; dstp = ei1 + E1c; E = E1c; nb = NB1; binB = NB0; }
    else { srcp = ei2; dstp = ei2 + E2c; E = E2c; nb = NB2; binB = NB0 + NB1; }
    for (int i = t; i < nb; i += 256) lc[i] = 0;
    __syncthreads();
    int e0 = bl * 4096, e1 = min(E, e0 + 4096);
    for (int i = e0 + t; i < e1; i += 256) atomicAdd(&lc[dstp[i] >> 10], 1);
    __syncthreads();
    for (int i = t; i < nb; i += 256) {
        int c = lc[i];
        lb[i] = c ? atomicAdd(&binCursor[binB + i], c) : 0;
        lc[i] = 0;   // reuse as local cursor
    }
    __syncthreads();
    for (int i = e0 + t; i < e1; i += 256) {
        int d = dstp[i];
        int bn = d >> 10;
        int p = atomicAdd(&lc[bn], 1);
        BE[lb[bn] + p] = make_int2(srcp[i], d);
    }
}

// ------------- phase D1: per-bin node counts -> CNT, DINV, padded bin total -------------
__global__ void kD1_count(const int2* __restrict__ BE, const int* __restrict__ binStart,
                          int* __restrict__ CNT, float* __restrict__ DINV,
                          int* __restrict__ binPadTot) {
    __shared__ int lc[1024];
    __shared__ int red[256];
    int b = blockIdx.x, t = threadIdx.x;
    int lv, bl; lvl_of_bin(b, lv, bl);
    int cbase, nLev;
    if (lv == 0) { cbase = 0; nLev = N0c; }
    else if (lv == 1) { cbase = N0c; nLev = N1c; }
    else { cbase = N0c + N1c; nLev = N2c; }
    for (int i = t; i < 1024; i += 256) lc[i] = 0;
    __syncthreads();
    int s0 = binStart[b], s1 = binStart[b + 1];
    for (int i = s0 + t; i < s1; i += 256) {
        int2 e = BE[i];
        atomicAdd(&lc[e.y & 1023], 1);
    }
    __syncthreads();
    int nodeB = bl << 10;
    int ps = 0;
#pragma unroll
    for (int j = 0; j < 4; j++) {
        int li = t * 4 + j;
        int node = nodeB + li;
        if (node < nLev) {
            int c = lc[li];
            CNT[cbase + node] = c;
            DINV[cbase + node] = rsqrtf((float)c + 1.0f);
            ps += (c + 3) & ~3;
        }
    }
    red[t] = ps;
    __syncthreads();
    for (int off = 128; off > 0; off >>= 1) {
        if (t < off) red[t] += red[t + off];
        __syncthreads();
    }
    if (t == 0) binPadTot[b] = red[0];
}

// ------------- phase D2: scan padded bin totals -> per-bin COL base (level-rebased) -------------
__global__ void kD2_scan(const int* __restrict__ binPadTot, int* __restrict__ binPadStart) {
    __shared__ int s[512];
    __shared__ int tot0, tot01;
    int t = threadIdx.x;
    int v = (t < NBt) ? binPadTot[t] : 0;
    s[t] = v;
    __syncthreads();
    for (int off = 1; off < 512; off <<= 1) {
        int x = (t >= off) ? s[t - off] : 0;
        __syncthreads();
        s[t] += x;
        __syncthreads();
    }
    if (t == 0) { tot0 = s[NB0 - 1]; tot01 = s[NB0 + NB1 - 1]; }
    __syncthreads();
    if (t < NBt) {
        int ex = s[t] - v;
        int cb, sub;
        if (t < NB0) { cb = 0; sub = 0; }
        else if (t < NB0 + NB1) { cb = P0c; sub = tot0; }
        else { cb = P0c + P1c; sub = tot01; }
        binPadStart[t] = cb + ex - sub;
    }
}

// ------------- phase D3: per-bin rowptr + COL scatter (all writes L2-hot) -------------
__global__ void kD3_final(const int2* __restrict__ BE, const int* __restrict__ binStart,
                          const int* __restrict__ CNT, const int* __restrict__ binPadStart,
                          int* __restrict__ rowptr, int* __restrict__ colAll) {
    __shared__ int lst[1024];
    __shared__ int lcur[1024];
    __shared__ int red[256];
    int b = blockIdx.x, t = threadIdx.x;
    int lv, bl; lvl_of_bin(b, lv, bl);
    int cbase, nLev, dummy;
    if (lv == 0) { cbase = 0; nLev = N0c; dummy = N0c; }
    else if (lv == 1) { cbase = N0c; nLev = N1c; dummy = N1c; }
    else { cbase = N0c + N1c; nLev = N2c; dummy = N2c; }
    int nodeB = bl << 10;
    int pc[4];
    int ps = 0;
#pragma unroll
    for (int j = 0; j < 4; j++) {
        int li = t * 4 + j;
        int node = nodeB + li;
        int c = (node < nLev) ? CNT[cbase + node] : 0;
        pc[j] = (c + 3) & ~3;
        ps += pc[j];
    }
    red[t] = ps;
    __syncthreads();
    for (int off = 1; off < 256; off <<= 1) {
        int x = (t >= off) ? red[t - off] : 0;
        __syncthreads();
        red[t] += x;
        __syncthreads();
    }
    int ex = red[t] - ps;
    int tot = red[255];
    int off = ex;
#pragma unroll
    for (int j = 0; j < 4; j++) {
        int li = t * 4 + j;
        lst[li] = off;
        lcur[li] = off;
        off += pc[j];
    }
    int cb = binPadStart[b];
#pragma unroll
    for (int j = 0; j < 4; j++) {
        int li = t * 4 + j;
        int node = nodeB + li;
        if (node < nLev) rowptr[cbase + node] = cb + lst[li];
    }
    __syncthreads();
    // fill bin COL region with dummy (pads survive the scatter)
    for (int i = t; i < tot; i += 256) colAll[cb + i] = dummy;
    __syncthreads();
    int s0 = binStart[b], s1 = binStart[b + 1];
    for (int i = s0 + t; i < s1; i += 256) {
        int2 e = BE[i];
        int p = atomicAdd(&lcur[e.y & 1023], 1);
        colAll[cb + p] = e.x;
    }
}

// ---------------- gather core: a = (ys[node] + sum ys[col]) * dinv[node] ----------------
__device__ __forceinline__ float gather4(const float* __restrict__ ys,
                                         const int* __restrict__ rp,
                                         const int* __restrict__ cnt,
                                         const int* __restrict__ col,
                                         const float* __restrict__ dinv,
                                         int node, int c) {
    int s0 = rp[node];
    int nch = (cnt[node] + 3) >> 2;
    float a = ys[(size_t)node * 32 + c];
    const int4* c4 = (const int4*)(col + s0);
    for (int i = 0; i < nch; i++) {
        int4 cs = c4[i];
        float a0 = ys[(size_t)cs.x * 32 + c];
        float a1 = ys[(size_t)cs.y * 32 + c];
        float a2 = ys[(size_t)cs.z * 32 + c];
        float a3 = ys[(size_t)cs.w * 32 + c];
        a += (a0 + a1) + (a2 + a3);
    }
    return a * dinv[node];
}

// ---------------- K1: fc1 + relu + prep1 ----------------
__global__ void k_fc1prep(const void* __restrict__ x, const void* __restrict__ fw,
                          const void* __restrict__ fb, const void* __restrict__ w1,
                          const float* __restrict__ d0, float* __restrict__ ys1,
                          const int* __restrict__ flag) {
    int isf32 = *flag;
    __shared__ float sx[32];
    __shared__ float sh[256];
    int t = threadIdx.x;
    int nodeBase = blockIdx.x * 8;
    if (t < 32) sx[t] = rdf(x, nodeBase * 4 + t, isf32);
    __syncthreads();
    int local = t >> 5, c = t & 31;
    float a = rdf(fb, c, isf32);
#pragma unroll
    for (int k = 0; k < 4; k++) a = fmaf(sx[local * 4 + k], rdf(fw, k * 32 + c, isf32), a);
    sh[t] = fmaxf(a, 0.0f);
    __syncthreads();
    float s = 0.0f;
#pragma unroll
    for (int k = 0; k < 32; k++) s = fmaf(sh[local * 32 + k], rdf(w1, k * 32 + c, isf32), s);
    int node = nodeBase + local;
    ys1[(size_t)node * 32 + c] = s * d0[node];
}

// ---------------- K2/K3: gather + relu -> O; fused prep_next on downsample ----------------
__global__ void k_gds(const float* __restrict__ ys_in, const int* __restrict__ rp,
                      const int* __restrict__ cnt, const int* __restrict__ col,
                      const float* __restrict__ dinv_p, const void* __restrict__ b,
                      float* __restrict__ O, const void* __restrict__ wn,
                      const float* __restrict__ dinv_c, float* __restrict__ ys_out,
                      int cols, const int* __restrict__ flag) {
    int isf32 = *flag;
    __shared__ float sv[256];
    int t = threadIdx.x;
    int nodeBase = blockIdx.x * 8;
    int local = t >> 5, c = t & 31;
    int node = nodeBase + local;
    float v = fmaxf(gather4(ys_in, rp, cnt, col, dinv_p, node, c) + rdf(b, c, isf32), 0.0f);
    O[(size_t)node * 32 + c] = v;
    sv[t] = v;
    __syncthreads();
    int rb = nodeBase / cols;
    if (!(rb & 1) && t < 128) {
        int row = t >> 5;
        int lc = row * 2;
        int cc = (nodeBase - rb * cols) + lc;
        int dn = (rb >> 1) * (cols >> 1) + (cc >> 1);
        int ci = t & 31;
        float a = 0.0f;
#pragma unroll
        for (int k = 0; k < 32; k++) a = fmaf(sv[lc * 32 + k], rdf(wn, k * 32 + ci, isf32), a);
        ys_out[(size_t)dn * 32 + ci] = a * dinv_c[dn];
    }
}

// ---------------- K4/K5: gather + up-residual + prep_next for 4 children ----------------
__global__ void k_gup(const float* __restrict__ ys_in, const int* __restrict__ rp,
                      const int* __restrict__ cnt, const int* __restrict__ col,
                      const float* __restrict__ dinv_p, const void* __restrict__ b,
                      const float* __restrict__ R, const void* __restrict__ wn,
                      const float* __restrict__ dinv_c, float* __restrict__ ys_out,
                      int cols_p, const int* __restrict__ flag) {
    int isf32 = *flag;
    __shared__ float sv[256];
    __shared__ float sch[1024];
    int t = threadIdx.x;
    int nodeBase = blockIdx.x * 8;
    int local = t >> 5, c = t & 31;
    int node = nodeBase + local;
    float v = fmaxf(gather4(ys_in, rp, cnt, col, dinv_p, node, c) + rdf(b, c, isf32), 0.0f);
    sv[t] = v;
    __syncthreads();
    int rb = nodeBase / cols_p;
    int ccb = nodeBase - rb * cols_p;
    int cols_c = cols_p * 2;
#pragma unroll
    for (int i = 0; i < 4; i++) {
        int item = t + i * 256;
        int row = item >> 5, k = item & 31;
        int lp = row >> 2, j = row & 3;
        int ch = (2 * rb + (j >> 1)) * cols_c + 2 * (ccb + lp) + (j & 1);
        sch[item] = R[(size_t)ch * 32 + k] + sv[lp * 32 + k];
    }
    __syncthreads();
#pragma unroll
    for (int i = 0; i < 4; i++) {
        int item = t + i * 256;
        int row = item >> 5, ci = item & 31;
        int lp = row >> 2, j = row & 3;
        int ch = (2 * rb + (j >> 1)) * cols_c + 2 * (ccb + lp) + (j & 1);
        float a = 0.0f;
#pragma unroll
        for (int k = 0; k < 32; k++) a = fmaf(sch[row * 32 + k], rdf(wn, k * 32 + ci, isf32), a);
        ys_out[(size_t)ch * 32 + ci] = a * dinv_c[ch];
    }
}

// ---------------- K6: gather + relu + fc2 -> out ----------------
__global__ void k_gfc2(const float* __restrict__ ys, const int* __restrict__ rp,
                       const int* __restrict__ cnt, const int* __restrict__ col,
                       const float* __restrict__ dinv, const void* __restrict__ b5,
                       const void* __restrict__ fw, const void* __restrict__ fb,
                       void* __restrict__ out, int n, const int* __restrict__ flag) {
    int isf32 = *flag;
    __shared__ float sv[256];
    __shared__ float sw[96];
    __shared__ float sfb[3];
    int t = threadIdx.x;
    if (t < 96) sw[t] = rdf(fw, t, isf32);
    if (t < 3) sfb[t] = rdf(fb, t, isf32);
    int node = blockIdx.x * 8 + (t >> 5);
    int c = t & 31;
    float v = fmaxf(gather4(ys, rp, cnt, col, dinv, node, c) + rdf(b5, c, isf32), 0.0f);
    sv[t] = v;
    __syncthreads();
    if (t < 24) {
        int ln = t / 3, j = t - ln * 3;
        int gn = blockIdx.x * 8 + ln;
        float o = sfb[j];
#pragma unroll
        for (int k = 0; k < 32; k++) o = fmaf(sv[ln * 32 + k], sw[k * 3 + j], o);
        if (isf32) ((float*)out)[(size_t)gn * 3 + j] = o;
        else ((u16*)out)[(size_t)gn * 3 + j] = f2bf(o);
    }
}

extern "C" void kernel_launch(void* const* d_in, const int* in_sizes, int n_in,
                              void* d_out, int out_size, void* d_ws, size_t ws_size,
                              hipStream_t stream) {
    const void* x    = d_in[0];
    const void* fc1w = d_in[1];
    const void* fc1b = d_in[2];
    const void* w1 = d_in[3];  const void* b1 = d_in[4];
    const void* w2 = d_in[5];  const void* b2 = d_in[6];
    const void* w3 = d_in[7];  const void* b3 = d_in[8];
    const void* w4 = d_in[9];  const void* b4 = d_in[10];
    const void* w5 = d_in[11]; const void* b5 = d_in[12];
    const void* fc2w = d_in[13]; const void* fc2b = d_in[14];
    const int* ei0 = (const int*)d_in[18];
    const int* ei1 = (const int*)d_in[19];
    const int* ei2 = (const int*)d_in[20];

    float* ws = (float*)d_ws;
    float* YS0  = ws;                           // (N0+1)*32
    float* A    = YS0 + (size_t)(N0c + 1) * 32; // N0*32
    float* YS1  = A   + (size_t)N0c * 32;       // (N1+1)*32
    float* H1   = YS1 + (size_t)(N1c + 1) * 32; // N1*32
    float* YS2  = H1  + (size_t)N1c * 32;       // (N2+1)*32
    float* DINV = YS2 + (size_t)(N2c + 1) * 32; // NT
    int* CNT   = (int*)(DINV + NTc);            // NT
    int* RPA   = CNT + NTc;                     // NT (rowptr, absolute into COLA)
    int* COLA  = RPA + NTc;                     // Ptot
    int2* BE   = (int2*)(COLA + Ptot);          // Etot (8B-aligned: prefix is even #ints)
    int* binCnt      = (int*)(BE + Etot);       // NBt
    int* binStart    = binCnt + NBt;            // NBt+1
    int* binCursor   = binStart + NBt + 1;      // NBt
    int* binPadTot   = binCursor + NBt;         // NBt
    int* binPadStart = binPadTot + NBt;         // NBt
    int* FLAG        = binPadStart + NBt;       // 1

    float* D0 = DINV; float* D1 = D0 + N0c; float* D2 = D1 + N1c;
    int* C0 = CNT;  int* C1 = C0 + N0c;  int* C2 = C1 + N1c;
    int* RP0 = RPA; int* RP1 = RP0 + N0c; int* RP2 = RP1 + N1c;

    const int Bk = 256;

    k_detect<<<1, 256, 0, stream>>>((const u32*)x, FLAG);
    k_init<<<2, 256, 0, stream>>>(binCnt, YS0 + (size_t)N0c * 32,
                                  YS1 + (size_t)N1c * 32, YS2 + (size_t)N2c * 32);

    // binned CSR build, all levels fused per phase
    kA_count<<<NBt, Bk, 0, stream>>>(ei0, ei1, ei2, binCnt);
    kB_scan<<<1, 512, 0, stream>>>(binCnt, binStart, binCursor);
    kC_place<<<NBt, Bk, 0, stream>>>(ei0, ei1, ei2, binCursor, BE);
    kD1_count<<<NBt, Bk, 0, stream>>>(BE, binStart, CNT, DINV, binPadTot);
    kD2_scan<<<1, 512, 0, stream>>>(binPadTot, binPadStart);
    kD3_final<<<NBt, Bk, 0, stream>>>(BE, binStart, CNT, binPadStart, RPA, COLA);

    // K1: fc1+relu+prep1 -> YS0
    k_fc1prep<<<N0c / 8, Bk, 0, stream>>>(x, fc1w, fc1b, w1, D0, YS0, FLAG);
    // K2: gather1 -> A (h_b), fused prep2 on downsample -> YS1
    k_gds<<<N0c / 8, Bk, 0, stream>>>(YS0, RP0, C0, COLA, D0, b1, A, w2, D1, YS1, NYg, FLAG);
    // K3: gather2 -> H1 (h1_b), fused prep3 on downsample -> YS2
    k_gds<<<N1c / 8, Bk, 0, stream>>>(YS1, RP1, C1, COLA, D1, b2, H1, w3, D2, YS2, NYg / 2, FLAG);
    // K4: gather3 (level2) + up-residual(H1) + prep4 -> YS1
    k_gup<<<N2c / 8, Bk, 0, stream>>>(YS2, RP2, C2, COLA, D2, b3, H1, w4, D1, YS1, NYg / 4, FLAG);
    // K5: gather4 (level1) + up-residual(A) + prep5 -> YS0
    k_gup<<<N1c / 8, Bk, 0, stream>>>(YS1, RP1, C1, COLA, D1, b4, A, w5, D0, YS0, NYg / 2, FLAG);
    // K6: gather5 + fc2 -> out
    k_gfc2<<<N0c / 8, Bk, 0, stream>>>(YS0, RP0, C0, COLA, D0, b5, fc2w, fc2b, d_out, N0c, FLAG);
}